// Round 3
// baseline (64545.312 us; speedup 1.0000x reference)
//
#include <hip/hip_runtime.h>

#define T_STEPS 24000
#define DIN 598
#define NU 100     // hidden units
#define NG 400     // 4 * NU gates
#define SLICE 28   // k-slice per thread (4 slices x 28 = 112 = padded K)
#define KPAD 112

// ---------------------------------------------------------------------------
// GEMM with bias: C[M,N] = A[M,K] @ B[K,N] + bias[N]   (fp32, 64x64 tile)
// ---------------------------------------------------------------------------
__global__ __launch_bounds__(256) void gemm_bias_kernel(
    const float* __restrict__ A, const float* __restrict__ B,
    const float* __restrict__ bias, float* __restrict__ C,
    int M, int N, int K)
{
    __shared__ float As[16][65];
    __shared__ float Bs[16][65];
    const int tid = threadIdx.x;
    const int tx = tid & 15;
    const int ty = tid >> 4;
    const int bm = blockIdx.y * 64;
    const int bn = blockIdx.x * 64;
    float acc[4][4] = {};

    for (int k0 = 0; k0 < K; k0 += 16) {
        #pragma unroll
        for (int p = 0; p < 4; ++p) {
            int e = tid + p * 256;
            int r = e >> 4, cc = e & 15;
            int m = bm + r, k = k0 + cc;
            float v = (m < M && k < K) ? A[(long)m * K + k] : 0.f;
            As[cc][r] = v;
        }
        #pragma unroll
        for (int p = 0; p < 4; ++p) {
            int e = tid + p * 256;
            int r = e >> 6, cc = e & 63;
            int k = k0 + r, n = bn + cc;
            float v = (k < K && n < N) ? B[(long)k * N + n] : 0.f;
            Bs[r][cc] = v;
        }
        __syncthreads();
        #pragma unroll
        for (int kk = 0; kk < 16; ++kk) {
            float a[4], b[4];
            #pragma unroll
            for (int i = 0; i < 4; ++i) a[i] = As[kk][ty * 4 + i];
            #pragma unroll
            for (int j = 0; j < 4; ++j) b[j] = Bs[kk][tx * 4 + j];
            #pragma unroll
            for (int i = 0; i < 4; ++i)
                #pragma unroll
                for (int j = 0; j < 4; ++j)
                    acc[i][j] += a[i] * b[j];
        }
        __syncthreads();
    }
    #pragma unroll
    for (int i = 0; i < 4; ++i) {
        int m = bm + ty * 4 + i;
        if (m >= M) continue;
        #pragma unroll
        for (int j = 0; j < 4; ++j) {
            int n = bn + tx * 4 + j;
            if (n < N) C[(long)m * N + n] = acc[i][j] + bias[n];
        }
    }
}

// ---------------------------------------------------------------------------
__device__ __forceinline__ float sigmoid_(float x) {
    return 1.f / (1.f + __expf(-x));
}
__device__ __forceinline__ float tanh_(float x) {
    float e = __expf(2.f * x);
    return 1.f - 2.f / (e + 1.f);
}

// ---------------------------------------------------------------------------
// Serial LSTM recurrence + fused BN.  One workgroup, 448 threads (7 waves).
//
// R2 restructure: thread tid = 4q+s computes columns {4q..4q+3} of z over
// k-slice [28s, 28s+28) (K padded 100->112 with zeros).  This cuts per-step
// LDS h-traffic 4x (179 KB -> 45 KB; R1 profile showed the step was LDS-
// return-bandwidth bound at ~2033 cyc/step).  Slice partials are reduced
// with an intra-quad shfl_xor butterfly (partners are adjacent lanes), so
// still only 2 barriers/step.  zact packed [unit][gate] for b128 phase-B read.
// ---------------------------------------------------------------------------
__global__ __launch_bounds__(448) void lstm_bn_kernel(
    const float* __restrict__ xW,     // [T, 400]
    const float* __restrict__ U,      // [100, 400] row-major
    const float* __restrict__ gamma, const float* __restrict__ beta,
    const float* __restrict__ mean,  const float* __restrict__ var,
    float* __restrict__ out)          // [T, 100]  (BN applied)
{
    __shared__ __align__(16) float h_pad[KPAD];     // h, zero-padded to 112
    __shared__ __align__(16) float zact[NU * 4];    // packed [unit][gate i,f,g,o]
    const int tid = threadIdx.x;
    const bool active = tid < NG;
    const int q = tid >> 2;          // column quad 0..99
    const int s = tid & 3;           // k-slice 0..3
    const int gate  = tid >= 300 ? 3 : tid >= 200 ? 2 : tid >= 100 ? 1 : 0;
    const int u_col = tid - gate * 100;   // unit index of this thread's column

    // U fragments: uf[i] = U[28s+i][4q .. 4q+3], zero rows for k >= 100
    float4 uf[SLICE];
    if (active) {
        const int k0 = s * SLICE;
        #pragma unroll
        for (int i = 0; i < SLICE; ++i) {
            int k = k0 + i;
            uf[i] = (k < NU) ? *(const float4*)&U[(long)k * NG + 4 * q]
                             : make_float4(0.f, 0.f, 0.f, 0.f);
        }
    }

    float c_state = 0.f, bsc = 0.f, bsh = 0.f;
    if (tid < NU) {
        float sc = gamma[tid] * rsqrtf(var[tid] + 1e-3f);
        bsc = sc;
        bsh = beta[tid] - mean[tid] * sc;
    }
    if (tid < KPAD) h_pad[tid] = 0.f;    // includes the zero pad
    __syncthreads();

    // depth-2 prefetch of xW rows (this thread's column = tid)
    float xw0 = active ? xW[tid] : 0.f;
    float xw1 = active ? xW[NG + tid] : 0.f;

    const float4* h4 = (const float4*)(h_pad + s * SLICE);  // s*112B, 16B-aligned

    for (int t = 0; t < T_STEPS; ++t) {
        float z = xw0;
        xw0 = xw1;
        if (active && t + 2 < T_STEPS) xw1 = xW[(long)(t + 2) * NG + tid];

        if (active) {
            float4 p = make_float4(0.f, 0.f, 0.f, 0.f);
            #pragma unroll
            for (int r = 0; r < 7; ++r) {
                float4 hv = h4[r];
                float hvals[4] = {hv.x, hv.y, hv.z, hv.w};
                #pragma unroll
                for (int c2 = 0; c2 < 4; ++c2) {
                    float4 uv = uf[4 * r + c2];
                    float hh = hvals[c2];
                    p.x += uv.x * hh;
                    p.y += uv.y * hh;
                    p.z += uv.z * hh;
                    p.w += uv.w * hh;
                }
            }
            // intra-quad butterfly: sum the 4 slice partials (lanes 4q+0..3)
            p.x += __shfl_xor(p.x, 1); p.y += __shfl_xor(p.y, 1);
            p.z += __shfl_xor(p.z, 1); p.w += __shfl_xor(p.w, 1);
            p.x += __shfl_xor(p.x, 2); p.y += __shfl_xor(p.y, 2);
            p.z += __shfl_xor(p.z, 2); p.w += __shfl_xor(p.w, 2);
            // this thread owns column 4q+s == tid
            float d = (s == 0) ? p.x : (s == 1) ? p.y : (s == 2) ? p.z : p.w;
            z += d;
            // Keras gate order i,f,g,o: gate 2 (g) -> tanh, others sigmoid
            float a = (gate == 2) ? tanh_(z) : sigmoid_(z);
            zact[u_col * 4 + gate] = a;
        }
        __syncthreads();   // zact complete; phase-A h reads of step t done

        if (tid < NU) {
            float4 zz = *(const float4*)&zact[tid * 4];   // i,f,g,o
            c_state = zz.y * c_state + zz.x * zz.z;
            float h = zz.w * tanh_(c_state);
            h_pad[tid] = h;
            out[(long)t * NU + tid] = h * bsc + bsh;      // fused BN
        }
        __syncthreads();   // h visible before next step's dot
    }
}

// ---------------------------------------------------------------------------
// Dense (100->3) + softmax over last dim.  One thread per timestep row.
// ---------------------------------------------------------------------------
__global__ __launch_bounds__(256) void dense_softmax_kernel(
    const float* __restrict__ H,   // [T, 100]
    const float* __restrict__ Wd,  // [100, 3]
    const float* __restrict__ bd,  // [3]
    float* __restrict__ out,       // [T, 3]
    int T)
{
    __shared__ float w[300];
    __shared__ float b[3];
    const int tid = threadIdx.x;
    for (int i = tid; i < 300; i += 256) w[i] = Wd[i];
    if (tid < 3) b[tid] = bd[tid];
    __syncthreads();

    int row = blockIdx.x * blockDim.x + tid;
    if (row >= T) return;
    const float* h = H + (long)row * NU;
    float s0 = b[0], s1 = b[1], s2 = b[2];
    #pragma unroll 4
    for (int k = 0; k < NU; ++k) {
        float hv = h[k];
        s0 += hv * w[3 * k + 0];
        s1 += hv * w[3 * k + 1];
        s2 += hv * w[3 * k + 2];
    }
    float m = fmaxf(s0, fmaxf(s1, s2));
    float e0 = __expf(s0 - m), e1 = __expf(s1 - m), e2 = __expf(s2 - m);
    float inv = 1.f / (e0 + e1 + e2);
    out[(long)row * 3 + 0] = e0 * inv;
    out[(long)row * 3 + 1] = e1 * inv;
    out[(long)row * 3 + 2] = e2 * inv;
}

// ---------------------------------------------------------------------------
extern "C" void kernel_launch(void* const* d_in, const int* in_sizes, int n_in,
                              void* d_out, int out_size, void* d_ws, size_t ws_size,
                              hipStream_t stream)
{
    const float* x   = (const float*)d_in[0];
    const float* W1  = (const float*)d_in[1];
    const float* U1  = (const float*)d_in[2];
    const float* b1  = (const float*)d_in[3];
    const float* ga1 = (const float*)d_in[4];
    const float* be1 = (const float*)d_in[5];
    const float* mu1 = (const float*)d_in[6];
    const float* va1 = (const float*)d_in[7];
    const float* W2  = (const float*)d_in[8];
    const float* U2  = (const float*)d_in[9];
    const float* b2  = (const float*)d_in[10];
    const float* ga2 = (const float*)d_in[11];
    const float* be2 = (const float*)d_in[12];
    const float* mu2 = (const float*)d_in[13];
    const float* va2 = (const float*)d_in[14];
    const float* W3  = (const float*)d_in[15];
    const float* U3  = (const float*)d_in[16];
    const float* b3  = (const float*)d_in[17];
    const float* ga3 = (const float*)d_in[18];
    const float* be3 = (const float*)d_in[19];
    const float* mu3 = (const float*)d_in[20];
    const float* va3 = (const float*)d_in[21];
    const float* Wd  = (const float*)d_in[22];
    const float* bd  = (const float*)d_in[23];

    float* xw = (float*)d_ws;                       // [24000,400]
    float* h1 = xw + (size_t)T_STEPS * NG;          // [24000,100]
    float* h2 = h1 + (size_t)T_STEPS * NU;          // [24000,100]
    float* h3 = h1;                                 // reuse (dead after xW2 GEMM)
    float* out = (float*)d_out;

    dim3 blk(256);
    dim3 grd((NG + 63) / 64, (T_STEPS + 63) / 64);

    gemm_bias_kernel<<<grd, blk, 0, stream>>>(x, W1, b1, xw, T_STEPS, NG, DIN);
    lstm_bn_kernel<<<1, 448, 0, stream>>>(xw, U1, ga1, be1, mu1, va1, h1);
    gemm_bias_kernel<<<grd, blk, 0, stream>>>(h1, W2, b2, xw, T_STEPS, NG, NU);
    lstm_bn_kernel<<<1, 448, 0, stream>>>(xw, U2, ga2, be2, mu2, va2, h2);
    gemm_bias_kernel<<<grd, blk, 0, stream>>>(h2, W3, b3, xw, T_STEPS, NG, NU);
    lstm_bn_kernel<<<1, 448, 0, stream>>>(xw, U3, ga3, be3, mu3, va3, h3);
    dense_softmax_kernel<<<(T_STEPS + 255) / 256, 256, 0, stream>>>(h3, Wd, bd, out, T_STEPS);
}

// Round 4
// 63706.860 us; speedup vs baseline: 1.0132x; 1.0132x over previous
//
#include <hip/hip_runtime.h>

#define T_STEPS 24000
#define DIN 598
#define NU 100     // hidden units
#define NG 400     // 4 * NU gates
#define SLICE 28   // k-slice per thread (4 slices x 28 = 112 = padded K)
#define KPAD 112

// LDS-only barrier: orders ds ops without draining global loads/stores.
// HIP __syncthreads() emits s_waitcnt vmcnt(0) before s_barrier, which put
// the xW prefetch + out-store latency (~2000 cyc) on the per-step critical
// path (R3 post-mortem: step time invariant to 4x LDS-traffic change).
#define BARRIER_LDS() asm volatile("s_waitcnt lgkmcnt(0)\n\ts_barrier" ::: "memory")

// ---------------------------------------------------------------------------
// GEMM with bias: C[M,N] = A[M,K] @ B[K,N] + bias[N]   (fp32, 64x64 tile)
// ---------------------------------------------------------------------------
__global__ __launch_bounds__(256) void gemm_bias_kernel(
    const float* __restrict__ A, const float* __restrict__ B,
    const float* __restrict__ bias, float* __restrict__ C,
    int M, int N, int K)
{
    __shared__ float As[16][65];
    __shared__ float Bs[16][65];
    const int tid = threadIdx.x;
    const int tx = tid & 15;
    const int ty = tid >> 4;
    const int bm = blockIdx.y * 64;
    const int bn = blockIdx.x * 64;
    float acc[4][4] = {};

    for (int k0 = 0; k0 < K; k0 += 16) {
        #pragma unroll
        for (int p = 0; p < 4; ++p) {
            int e = tid + p * 256;
            int r = e >> 4, cc = e & 15;
            int m = bm + r, k = k0 + cc;
            float v = (m < M && k < K) ? A[(long)m * K + k] : 0.f;
            As[cc][r] = v;
        }
        #pragma unroll
        for (int p = 0; p < 4; ++p) {
            int e = tid + p * 256;
            int r = e >> 6, cc = e & 63;
            int k = k0 + r, n = bn + cc;
            float v = (k < K && n < N) ? B[(long)k * N + n] : 0.f;
            Bs[r][cc] = v;
        }
        __syncthreads();
        #pragma unroll
        for (int kk = 0; kk < 16; ++kk) {
            float a[4], b[4];
            #pragma unroll
            for (int i = 0; i < 4; ++i) a[i] = As[kk][ty * 4 + i];
            #pragma unroll
            for (int j = 0; j < 4; ++j) b[j] = Bs[kk][tx * 4 + j];
            #pragma unroll
            for (int i = 0; i < 4; ++i)
                #pragma unroll
                for (int j = 0; j < 4; ++j)
                    acc[i][j] += a[i] * b[j];
        }
        __syncthreads();
    }
    #pragma unroll
    for (int i = 0; i < 4; ++i) {
        int m = bm + ty * 4 + i;
        if (m >= M) continue;
        #pragma unroll
        for (int j = 0; j < 4; ++j) {
            int n = bn + tx * 4 + j;
            if (n < N) C[(long)m * N + n] = acc[i][j] + bias[n];
        }
    }
}

// ---------------------------------------------------------------------------
__device__ __forceinline__ float sigmoid_(float x) {
    return 1.f / (1.f + __expf(-x));
}
__device__ __forceinline__ float tanh_(float x) {
    float e = __expf(2.f * x);
    return 1.f - 2.f / (e + 1.f);
}

// ---------------------------------------------------------------------------
// Serial LSTM recurrence + fused BN.  One workgroup, 448 threads (7 waves).
//
// R4 layout: thread tid = 4u+s owns unit u, slot s.  It computes the dot
// contribution of k-slice [28s,28s+28) for ALL FOUR gate-columns of unit u
// (cols {u, 100+u, 200+u, 300+u}), plus loads xW for gate s.  The intra-quad
// shfl_xor butterfly then gives every lane of quad u the complete (i,f,g,o)
// pre-activations -> each lane redundantly computes c/h (c replicated,
// bit-identical).  No zact LDS round-trip; h double-buffered in LDS ->
// ONE LDS-only barrier per step, no global-memory drain.
// ---------------------------------------------------------------------------
__global__ __launch_bounds__(448) void lstm_bn_kernel(
    const float* __restrict__ xW,     // [T, 400]
    const float* __restrict__ U,      // [100, 400] row-major
    const float* __restrict__ gamma, const float* __restrict__ beta,
    const float* __restrict__ mean,  const float* __restrict__ var,
    float* __restrict__ out)          // [T, 100]  (BN applied)
{
    __shared__ __align__(16) float hbuf0[KPAD];   // h double buffer (+pad to 112)
    __shared__ __align__(16) float hbuf1[KPAD];
    const int tid = threadIdx.x;
    const bool active = tid < NG;     // 400 workers
    const int u = tid >> 2;           // unit 0..99 (quad index)
    const int s = tid & 3;            // slot: k-slice AND gate for xW load
    const int col = s * NU + u;       // xW column this thread fetches

    // U fragments: uf[i].{x,y,z,w} = U[28s+i][{0,100,200,300}+u], zeros k>=100
    float4 uf[SLICE];
    if (active) {
        const int k0 = s * SLICE;
        #pragma unroll
        for (int i = 0; i < SLICE; ++i) {
            int k = k0 + i;
            if (k < NU) {
                const float* row = &U[(long)k * NG + u];
                uf[i] = make_float4(row[0], row[NU], row[2 * NU], row[3 * NU]);
            } else {
                uf[i] = make_float4(0.f, 0.f, 0.f, 0.f);
            }
        }
    }

    float c_state = 0.f, bsc = 0.f, bsh = 0.f;
    if (active) {
        float sc = gamma[u] * rsqrtf(var[u] + 1e-3f);
        bsc = sc;
        bsh = beta[u] - mean[u] * sc;
    }
    if (tid < KPAD) { hbuf0[tid] = 0.f; hbuf1[tid] = 0.f; }

    // depth-2 xW prefetch (this thread's gate-s column)
    float xw0 = active ? xW[col] : 0.f;
    float xw1 = active ? xW[NG + col] : 0.f;

    __syncthreads();   // one full barrier at init is fine

    auto step = [&](const float* __restrict__ hrd, float* __restrict__ hwr, int t) {
        if (active) {
            const float4* h4 = (const float4*)(hrd + s * SLICE);
            float4 p = make_float4(0.f, 0.f, 0.f, 0.f);
            #pragma unroll
            for (int r = 0; r < 7; ++r) {
                float4 hv = h4[r];
                float hvals[4] = {hv.x, hv.y, hv.z, hv.w};
                #pragma unroll
                for (int c2 = 0; c2 < 4; ++c2) {
                    float4 uv = uf[4 * r + c2];
                    float hh = hvals[c2];
                    p.x += uv.x * hh;
                    p.y += uv.y * hh;
                    p.z += uv.z * hh;
                    p.w += uv.w * hh;
                }
            }
            // fold this lane's xW (gate s) into component s, then butterfly
            if      (s == 0) p.x += xw0;
            else if (s == 1) p.y += xw0;
            else if (s == 2) p.z += xw0;
            else             p.w += xw0;
            xw0 = xw1;
            if (t + 2 < T_STEPS) xw1 = xW[(long)(t + 2) * NG + col];

            p.x += __shfl_xor(p.x, 1); p.y += __shfl_xor(p.y, 1);
            p.z += __shfl_xor(p.z, 1); p.w += __shfl_xor(p.w, 1);
            p.x += __shfl_xor(p.x, 2); p.y += __shfl_xor(p.y, 2);
            p.z += __shfl_xor(p.z, 2); p.w += __shfl_xor(p.w, 2);
            // all 4 lanes of quad u now hold complete z_i,z_f,z_g,z_o
            float iv = sigmoid_(p.x);
            float fv = sigmoid_(p.y);
            float gv = tanh_(p.z);
            float ov = sigmoid_(p.w);
            c_state = fv * c_state + iv * gv;           // replicated per quad
            float h = ov * tanh_(c_state);
            if (s == 0) {
                hwr[u] = h;                              // pad [100..111] stays 0
                out[(long)t * NU + u] = h * bsc + bsh;   // fused BN, fire+forget
            }
        }
        BARRIER_LDS();   // LDS-only: xW prefetch + out store stay in flight
    };

    for (int t = 0; t < T_STEPS; t += 2) {
        step(hbuf0, hbuf1, t);
        step(hbuf1, hbuf0, t + 1);
    }
}

// ---------------------------------------------------------------------------
// Dense (100->3) + softmax over last dim.  One thread per timestep row.
// ---------------------------------------------------------------------------
__global__ __launch_bounds__(256) void dense_softmax_kernel(
    const float* __restrict__ H,   // [T, 100]
    const float* __restrict__ Wd,  // [100, 3]
    const float* __restrict__ bd,  // [3]
    float* __restrict__ out,       // [T, 3]
    int T)
{
    __shared__ float w[300];
    __shared__ float b[3];
    const int tid = threadIdx.x;
    for (int i = tid; i < 300; i += 256) w[i] = Wd[i];
    if (tid < 3) b[tid] = bd[tid];
    __syncthreads();

    int row = blockIdx.x * blockDim.x + tid;
    if (row >= T) return;
    const float* h = H + (long)row * NU;
    float s0 = b[0], s1 = b[1], s2 = b[2];
    #pragma unroll 4
    for (int k = 0; k < NU; ++k) {
        float hv = h[k];
        s0 += hv * w[3 * k + 0];
        s1 += hv * w[3 * k + 1];
        s2 += hv * w[3 * k + 2];
    }
    float m = fmaxf(s0, fmaxf(s1, s2));
    float e0 = __expf(s0 - m), e1 = __expf(s1 - m), e2 = __expf(s2 - m);
    float inv = 1.f / (e0 + e1 + e2);
    out[(long)row * 3 + 0] = e0 * inv;
    out[(long)row * 3 + 1] = e1 * inv;
    out[(long)row * 3 + 2] = e2 * inv;
}

// ---------------------------------------------------------------------------
extern "C" void kernel_launch(void* const* d_in, const int* in_sizes, int n_in,
                              void* d_out, int out_size, void* d_ws, size_t ws_size,
                              hipStream_t stream)
{
    const float* x   = (const float*)d_in[0];
    const float* W1  = (const float*)d_in[1];
    const float* U1  = (const float*)d_in[2];
    const float* b1  = (const float*)d_in[3];
    const float* ga1 = (const float*)d_in[4];
    const float* be1 = (const float*)d_in[5];
    const float* mu1 = (const float*)d_in[6];
    const float* va1 = (const float*)d_in[7];
    const float* W2  = (const float*)d_in[8];
    const float* U2  = (const float*)d_in[9];
    const float* b2  = (const float*)d_in[10];
    const float* ga2 = (const float*)d_in[11];
    const float* be2 = (const float*)d_in[12];
    const float* mu2 = (const float*)d_in[13];
    const float* va2 = (const float*)d_in[14];
    const float* W3  = (const float*)d_in[15];
    const float* U3  = (const float*)d_in[16];
    const float* b3  = (const float*)d_in[17];
    const float* ga3 = (const float*)d_in[18];
    const float* be3 = (const float*)d_in[19];
    const float* mu3 = (const float*)d_in[20];
    const float* va3 = (const float*)d_in[21];
    const float* Wd  = (const float*)d_in[22];
    const float* bd  = (const float*)d_in[23];

    float* xw = (float*)d_ws;                       // [24000,400]
    float* h1 = xw + (size_t)T_STEPS * NG;          // [24000,100]
    float* h2 = h1 + (size_t)T_STEPS * NU;          // [24000,100]
    float* h3 = h1;                                 // reuse (dead after xW2 GEMM)
    float* out = (float*)d_out;

    dim3 blk(256);
    dim3 grd((NG + 63) / 64, (T_STEPS + 63) / 64);

    gemm_bias_kernel<<<grd, blk, 0, stream>>>(x, W1, b1, xw, T_STEPS, NG, DIN);
    lstm_bn_kernel<<<1, 448, 0, stream>>>(xw, U1, ga1, be1, mu1, va1, h1);
    gemm_bias_kernel<<<grd, blk, 0, stream>>>(h1, W2, b2, xw, T_STEPS, NG, NU);
    lstm_bn_kernel<<<1, 448, 0, stream>>>(xw, U2, ga2, be2, mu2, va2, h2);
    gemm_bias_kernel<<<grd, blk, 0, stream>>>(h2, W3, b3, xw, T_STEPS, NG, NU);
    lstm_bn_kernel<<<1, 448, 0, stream>>>(xw, U3, ga3, be3, mu3, va3, h3);
    dense_softmax_kernel<<<(T_STEPS + 255) / 256, 256, 0, stream>>>(h3, Wd, bd, out, T_STEPS);
}

// Round 5
// 24148.384 us; speedup vs baseline: 2.6729x; 2.6381x over previous
//
#include <hip/hip_runtime.h>

#define T_STEPS 24000
#define DIN 598
#define NU 100     // hidden units
#define NG 400     // 4 * NU gates
#define SLICE 28   // k-slice per thread (4 x 28 = 112 = padded K)
#define KPAD 112
#define CHUNK 120  // steps per pipeline chunk (even; CHUNK*NCHUNK == T_STEPS)
#define NCHUNK 200
#define RING 8     // ring capacity in chunks
#define RN (RING * CHUNK)   // 960 ring rows

// LDS-only barrier: orders ds ops without draining global loads/stores.
#define BARRIER_LDS() asm volatile("s_waitcnt lgkmcnt(0)\n\ts_barrier" ::: "memory")

// ---------------------------------------------------------------------------
// cross-WG sync helpers (device-scope; per-XCD L2s are non-coherent)
// ---------------------------------------------------------------------------
__device__ __forceinline__ void wg_wait_ge(int* flag, int target) {
    if (threadIdx.x == 0) {
        while (__hip_atomic_load(flag, __ATOMIC_RELAXED, __HIP_MEMORY_SCOPE_AGENT) < target)
            __builtin_amdgcn_s_sleep(2);
    }
    __syncthreads();                                   // all lanes held until flag seen
    __builtin_amdgcn_fence(__ATOMIC_ACQUIRE, "agent"); // invalidate stale L1/L2
}
__device__ __forceinline__ void wg_publish(int* a, int va, int* b, int vb) {
    __syncthreads();   // drains vmcnt(0): all lanes' global stores/loads complete
    if (threadIdx.x == 0) {
        if (a) __hip_atomic_store(a, va, __ATOMIC_RELEASE, __HIP_MEMORY_SCOPE_AGENT);
        if (b) __hip_atomic_store(b, vb, __ATOMIC_RELEASE, __HIP_MEMORY_SCOPE_AGENT);
    }
}

// ---------------------------------------------------------------------------
__device__ __forceinline__ float sigmoid_(float x) {
    return 1.f / (1.f + __expf(-x));
}
__device__ __forceinline__ float tanh_(float x) {
    float e = __expf(2.f * x);
    return 1.f - 2.f / (e + 1.f);
}
__device__ __forceinline__ float sel4(float4 p, int s) {
    return (s == 0) ? p.x : (s == 1) ? p.y : (s == 2) ? p.z : p.w;
}

// ---------------------------------------------------------------------------
// GEMM with bias: C[M,N] = A[M,K] @ B[K,N] + bias[N]   (fp32, 64x64 tile)
// ---------------------------------------------------------------------------
__global__ __launch_bounds__(256) void gemm_bias_kernel(
    const float* __restrict__ A, const float* __restrict__ B,
    const float* __restrict__ bias, float* __restrict__ C,
    int M, int N, int K)
{
    __shared__ float As[16][65];
    __shared__ float Bs[16][65];
    const int tid = threadIdx.x;
    const int tx = tid & 15;
    const int ty = tid >> 4;
    const int bm = blockIdx.y * 64;
    const int bn = blockIdx.x * 64;
    float acc[4][4] = {};

    for (int k0 = 0; k0 < K; k0 += 16) {
        #pragma unroll
        for (int p = 0; p < 4; ++p) {
            int e = tid + p * 256;
            int r = e >> 4, cc = e & 15;
            int m = bm + r, k = k0 + cc;
            float v = (m < M && k < K) ? A[(long)m * K + k] : 0.f;
            As[cc][r] = v;
        }
        #pragma unroll
        for (int p = 0; p < 4; ++p) {
            int e = tid + p * 256;
            int r = e >> 6, cc = e & 63;
            int k = k0 + r, n = bn + cc;
            float v = (k < K && n < N) ? B[(long)k * N + n] : 0.f;
            Bs[r][cc] = v;
        }
        __syncthreads();
        #pragma unroll
        for (int kk = 0; kk < 16; ++kk) {
            float a[4], b[4];
            #pragma unroll
            for (int i = 0; i < 4; ++i) a[i] = As[kk][ty * 4 + i];
            #pragma unroll
            for (int j = 0; j < 4; ++j) b[j] = Bs[kk][tx * 4 + j];
            #pragma unroll
            for (int i = 0; i < 4; ++i)
                #pragma unroll
                for (int j = 0; j < 4; ++j)
                    acc[i][j] += a[i] * b[j];
        }
        __syncthreads();
    }
    #pragma unroll
    for (int i = 0; i < 4; ++i) {
        int m = bm + ty * 4 + i;
        if (m >= M) continue;
        #pragma unroll
        for (int j = 0; j < 4; ++j) {
            int n = bn + tx * 4 + j;
            if (n < N) C[(long)m * N + n] = acc[i][j] + bias[n];
        }
    }
}

// ---------------------------------------------------------------------------
// Recurrent role: R4 step math (thread 4u+s, quad butterfly, redundant c/h),
// raw h written out (BN folded into downstream consumer's weights).
// ---------------------------------------------------------------------------
__device__ void rec_role(
    const float* __restrict__ xz, int xz_ring,   // [T][400] or ring [RN][400]
    const float* __restrict__ U,                 // [100][400]
    float* __restrict__ hout, int h_ring,        // [T][100] or ring [RN][100]
    int* flag_up,    // producer progress of xz (null: precomputed full buffer)
    int* done_self,  // publish: xz chunk consumed (null if no ring upstream)
    int* done_down,  // consumer progress on my h ring (null if hout full)
    int* flag_self,  // publish: h chunk produced (null for last layer)
    float* lds)      // >= 2*KPAD floats
{
    float* hb0 = lds;
    float* hb1 = lds + KPAD;
    const int tid = threadIdx.x;
    const bool active = tid < NG;
    const int u = tid >> 2;
    const int s = tid & 3;
    const int col = s * NU + u;

    float4 uf[SLICE];
    if (active) {
        const int k0 = s * SLICE;
        #pragma unroll
        for (int i = 0; i < SLICE; ++i) {
            int k = k0 + i;
            if (k < NU) {
                const float* row = &U[(long)k * NG + u];
                uf[i] = make_float4(row[0], row[NU], row[2 * NU], row[3 * NU]);
            } else {
                uf[i] = make_float4(0.f, 0.f, 0.f, 0.f);
            }
        }
    }
    if (tid < KPAD) { hb0[tid] = 0.f; hb1[tid] = 0.f; }
    float c_state = 0.f, xw0 = 0.f, xw1 = 0.f;
    __syncthreads();

    auto step = [&](const float* hrd, float* hwr, int t) {
        if (active) {
            const float4* h4 = (const float4*)(hrd + s * SLICE);
            float4 p = make_float4(0.f, 0.f, 0.f, 0.f);
            #pragma unroll
            for (int r = 0; r < 7; ++r) {
                float4 hv = h4[r];
                float hvals[4] = {hv.x, hv.y, hv.z, hv.w};
                #pragma unroll
                for (int c2 = 0; c2 < 4; ++c2) {
                    float4 uv = uf[4 * r + c2];
                    float hh = hvals[c2];
                    p.x += uv.x * hh;
                    p.y += uv.y * hh;
                    p.z += uv.z * hh;
                    p.w += uv.w * hh;
                }
            }
            if      (s == 0) p.x += xw0;
            else if (s == 1) p.y += xw0;
            else if (s == 2) p.z += xw0;
            else             p.w += xw0;
            xw0 = xw1;
            int tp = t + 2;
            if (tp < T_STEPS) {
                long rr = xz_ring ? (tp % RN) : tp;
                xw1 = xz[rr * NG + col];
            }
            p.x += __shfl_xor(p.x, 1); p.y += __shfl_xor(p.y, 1);
            p.z += __shfl_xor(p.z, 1); p.w += __shfl_xor(p.w, 1);
            p.x += __shfl_xor(p.x, 2); p.y += __shfl_xor(p.y, 2);
            p.z += __shfl_xor(p.z, 2); p.w += __shfl_xor(p.w, 2);
            float iv = sigmoid_(p.x);
            float fv = sigmoid_(p.y);
            float gv = tanh_(p.z);
            float ov = sigmoid_(p.w);
            c_state = fv * c_state + iv * gv;
            float h = ov * tanh_(c_state);
            if (s == 0) {
                hwr[u] = h;
                long orow = h_ring ? (t % RN) : t;
                hout[orow * NU + u] = h;     // raw h; BN folded downstream
            }
        }
        BARRIER_LDS();
    };

    for (int c = 0; c < NCHUNK; ++c) {
        if (flag_up) {
            int tgt = c + 2; if (tgt > NCHUNK) tgt = NCHUNK;   // prefetch crosses chunk
            wg_wait_ge(flag_up, tgt);
        }
        if (done_down && c >= RING) wg_wait_ge(done_down, c - RING + 1);
        if (c == 0 && active) {      // initial depth-2 prefetch (safe: flag >= 2 held)
            xw0 = xz[col];
            xw1 = xz[NG + col];
        }
        const int t0 = c * CHUNK;
        for (int tt = 0; tt < CHUNK; tt += 2) {
            step(hb0, hb1, t0 + tt);
            step(hb1, hb0, t0 + tt + 1);
        }
        wg_publish(done_self, c + 1, flag_self, c + 1);
    }
}

// ---------------------------------------------------------------------------
// Projection role: xz[t][j] = sum_k (bsc[k]*W[k][j]) * h[t][k] + (b[j] + sum_k bsh[k]*W[k][j])
// (upstream BN folded into weights/bias).  Steps independent -> pure throughput.
// ---------------------------------------------------------------------------
__device__ void proj_role(
    const float* __restrict__ hin,     // ring [RN][100]
    const float* __restrict__ W,       // [100][400]
    const float* __restrict__ bias,    // [400]
    const float* __restrict__ g, const float* __restrict__ be,
    const float* __restrict__ m, const float* __restrict__ v,
    float* __restrict__ xzout,         // ring [RN][400]
    int* flag_up, int* done_self, int* done_down, int* flag_self,
    float* lds)                         // CHUNK*KPAD floats
{
    const int tid = threadIdx.x;
    const bool active = tid < NG;
    const int u = tid >> 2;
    const int s = tid & 3;
    const int col = s * NU + u;

    float4 wf[SLICE];
    float bcol = 0.f;
    if (active) {
        const int k0 = s * SLICE;
        float4 pb = make_float4(0.f, 0.f, 0.f, 0.f);
        #pragma unroll
        for (int i = 0; i < SLICE; ++i) {
            int k = k0 + i;
            if (k < NU) {
                float sc = g[k] * rsqrtf(v[k] + 1e-3f);
                float sh = be[k] - m[k] * sc;
                const float* row = &W[(long)k * NG + u];
                wf[i] = make_float4(sc * row[0], sc * row[NU],
                                    sc * row[2 * NU], sc * row[3 * NU]);
                pb.x += sh * row[0];
                pb.y += sh * row[NU];
                pb.z += sh * row[2 * NU];
                pb.w += sh * row[3 * NU];
            } else {
                wf[i] = make_float4(0.f, 0.f, 0.f, 0.f);
            }
        }
        pb.x += __shfl_xor(pb.x, 1); pb.y += __shfl_xor(pb.y, 1);
        pb.z += __shfl_xor(pb.z, 1); pb.w += __shfl_xor(pb.w, 1);
        pb.x += __shfl_xor(pb.x, 2); pb.y += __shfl_xor(pb.y, 2);
        pb.z += __shfl_xor(pb.z, 2); pb.w += __shfl_xor(pb.w, 2);
        bcol = bias[col] + sel4(pb, s);
    }

    for (int c = 0; c < NCHUNK; ++c) {
        wg_wait_ge(flag_up, c + 1);
        if (c >= RING) wg_wait_ge(done_down, c - RING + 1);
        // stage h chunk c into LDS (pad k in [100,112) with zeros)
        const float* src = hin + (size_t)(c % RING) * CHUNK * NU;
        for (int idx = tid; idx < CHUNK * KPAD; idx += 448) {
            int r = idx / KPAD, k = idx - r * KPAD;
            lds[idx] = (k < NU) ? src[r * NU + k] : 0.f;
        }
        wg_publish(done_self, c + 1, (int*)0, 0);   // syncthreads inside; h slot free
        if (active) {
            float* ob = xzout + (size_t)(c % RING) * CHUNK * NG;
            for (int r = 0; r < CHUNK; ++r) {
                const float4* h4 = (const float4*)(lds + r * KPAD + s * SLICE);
                float4 p = make_float4(0.f, 0.f, 0.f, 0.f);
                #pragma unroll
                for (int i = 0; i < 7; ++i) {
                    float4 hv = h4[i];
                    float hvals[4] = {hv.x, hv.y, hv.z, hv.w};
                    #pragma unroll
                    for (int c2 = 0; c2 < 4; ++c2) {
                        float4 wv = wf[4 * i + c2];
                        float hh = hvals[c2];
                        p.x += wv.x * hh;
                        p.y += wv.y * hh;
                        p.z += wv.z * hh;
                        p.w += wv.w * hh;
                    }
                }
                p.x += __shfl_xor(p.x, 1); p.y += __shfl_xor(p.y, 1);
                p.z += __shfl_xor(p.z, 1); p.w += __shfl_xor(p.w, 1);
                p.x += __shfl_xor(p.x, 2); p.y += __shfl_xor(p.y, 2);
                p.z += __shfl_xor(p.z, 2); p.w += __shfl_xor(p.w, 2);
                ob[(long)r * NG + col] = sel4(p, s) + bcol;
            }
        }
        wg_publish(flag_self, c + 1, (int*)0, 0);   // xz chunk visible
    }
}

// ---------------------------------------------------------------------------
// Persistent pipeline: block 0..4 = rec1, proj2, rec2, proj3, rec3.
// ---------------------------------------------------------------------------
__global__ __launch_bounds__(448) void lstm_pipe_kernel(
    const float* xw1, const float* U1,
    const float* U2, const float* W2, const float* b2,
    const float* U3, const float* W3, const float* b3,
    const float* g1, const float* be1, const float* m1, const float* v1,
    const float* g2, const float* be2, const float* m2, const float* v2,
    float* h1r, float* h2r, float* xz2r, float* xz3r, float* h3,
    int* f)
{
    extern __shared__ float smem[];
    int* f_h1  = f +   0;   // rec1  produced h1 chunks
    int* d_p2  = f +  32;   // proj2 consumed h1 chunks
    int* f_xz2 = f +  64;   // proj2 produced xz2 chunks
    int* d_r2  = f +  96;   // rec2  consumed xz2 chunks
    int* f_h2  = f + 128;   // rec2  produced h2 chunks
    int* d_p3  = f + 160;   // proj3 consumed h2 chunks
    int* f_xz3 = f + 192;   // proj3 produced xz3 chunks
    int* d_r3  = f + 224;   // rec3  consumed xz3 chunks

    switch (blockIdx.x) {
    case 0: rec_role(xw1, 0, U1, h1r, 1, (int*)0, (int*)0, d_p2, f_h1, smem); break;
    case 1: proj_role(h1r, W2, b2, g1, be1, m1, v1, xz2r, f_h1, d_p2, d_r2, f_xz2, smem); break;
    case 2: rec_role(xz2r, 1, U2, h2r, 1, f_xz2, d_r2, d_p3, f_h2, smem); break;
    case 3: proj_role(h2r, W3, b3, g2, be2, m2, v2, xz3r, f_h2, d_p3, d_r3, f_xz3, smem); break;
    case 4: rec_role(xz3r, 1, U3, h3, 0, f_xz3, d_r3, (int*)0, (int*)0, smem); break;
    }
}

// ---------------------------------------------------------------------------
// Dense (100->3) + softmax, with BN3 folded into Wd/bd.
// ---------------------------------------------------------------------------
__global__ __launch_bounds__(256) void dense_softmax_kernel(
    const float* __restrict__ H,    // [T, 100] raw h3
    const float* __restrict__ Wd,   // [100, 3]
    const float* __restrict__ bd,   // [3]
    const float* __restrict__ g3, const float* __restrict__ be3,
    const float* __restrict__ m3, const float* __restrict__ v3,
    float* __restrict__ out, int T)
{
    __shared__ float w[300];
    __shared__ float b[3];
    const int tid = threadIdx.x;
    for (int i = tid; i < 300; i += 256) {
        int k = i / 3;
        float sc = g3[k] * rsqrtf(v3[k] + 1e-3f);
        w[i] = Wd[i] * sc;
    }
    if (tid < 3) {
        float acc = bd[tid];
        for (int k = 0; k < NU; ++k) {
            float sc = g3[k] * rsqrtf(v3[k] + 1e-3f);
            float sh = be3[k] - m3[k] * sc;
            acc += sh * Wd[3 * k + tid];
        }
        b[tid] = acc;
    }
    __syncthreads();

    int row = blockIdx.x * blockDim.x + tid;
    if (row >= T) return;
    const float* h = H + (long)row * NU;
    float s0 = b[0], s1 = b[1], s2 = b[2];
    #pragma unroll 4
    for (int k = 0; k < NU; ++k) {
        float hv = h[k];
        s0 += hv * w[3 * k + 0];
        s1 += hv * w[3 * k + 1];
        s2 += hv * w[3 * k + 2];
    }
    float mx = fmaxf(s0, fmaxf(s1, s2));
    float e0 = __expf(s0 - mx), e1 = __expf(s1 - mx), e2 = __expf(s2 - mx);
    float inv = 1.f / (e0 + e1 + e2);
    out[(long)row * 3 + 0] = e0 * inv;
    out[(long)row * 3 + 1] = e1 * inv;
    out[(long)row * 3 + 2] = e2 * inv;
}

// ---------------------------------------------------------------------------
extern "C" void kernel_launch(void* const* d_in, const int* in_sizes, int n_in,
                              void* d_out, int out_size, void* d_ws, size_t ws_size,
                              hipStream_t stream)
{
    const float* x   = (const float*)d_in[0];
    const float* W1  = (const float*)d_in[1];
    const float* U1  = (const float*)d_in[2];
    const float* b1  = (const float*)d_in[3];
    const float* ga1 = (const float*)d_in[4];
    const float* be1 = (const float*)d_in[5];
    const float* mu1 = (const float*)d_in[6];
    const float* va1 = (const float*)d_in[7];
    const float* W2  = (const float*)d_in[8];
    const float* U2  = (const float*)d_in[9];
    const float* b2  = (const float*)d_in[10];
    const float* ga2 = (const float*)d_in[11];
    const float* be2 = (const float*)d_in[12];
    const float* mu2 = (const float*)d_in[13];
    const float* va2 = (const float*)d_in[14];
    const float* W3  = (const float*)d_in[15];
    const float* U3  = (const float*)d_in[16];
    const float* b3  = (const float*)d_in[17];
    const float* ga3 = (const float*)d_in[18];
    const float* be3 = (const float*)d_in[19];
    const float* mu3 = (const float*)d_in[20];
    const float* va3 = (const float*)d_in[21];
    const float* Wd  = (const float*)d_in[22];
    const float* bd  = (const float*)d_in[23];

    // workspace layout (floats) — total ~51.8 MB (<57.6 MB proven in R2-R4)
    float* xw1  = (float*)d_ws;                       // T*400      = 9,600,000
    float* h3   = xw1  + (size_t)T_STEPS * NG;        // T*100      = 2,400,000
    float* h1r  = h3   + (size_t)T_STEPS * NU;        // RN*100     =    96,000
    float* h2r  = h1r  + (size_t)RN * NU;             //    96,000
    float* xz2r = h2r  + (size_t)RN * NU;             // RN*400     =   384,000
    float* xz3r = xz2r + (size_t)RN * NG;             //   384,000
    int*   flags = (int*)(xz3r + (size_t)RN * NG);    // 256 ints
    float* out = (float*)d_out;

    dim3 blk(256);
    dim3 grd((NG + 63) / 64, (T_STEPS + 63) / 64);

    // 1) input projection of layer 1 (dense GEMM, includes b1)
    gemm_bias_kernel<<<grd, blk, 0, stream>>>(x, W1, b1, xw1, T_STEPS, NG, DIN);
    // 2) zero the pipeline flags (ws is re-poisoned 0xAA before every launch)
    hipMemsetAsync(flags, 0, 256 * sizeof(int), stream);
    // 3) persistent 5-WG pipeline (5 blocks << 256 CUs -> co-resident)
    lstm_pipe_kernel<<<5, 448, CHUNK * KPAD * sizeof(float), stream>>>(
        xw1, U1, U2, W2, b2, U3, W3, b3,
        ga1, be1, mu1, va1, ga2, be2, mu2, va2,
        h1r, h2r, xz2r, xz3r, h3, flags);
    // 4) dense + softmax (BN3 folded)
    dense_softmax_kernel<<<(T_STEPS + 255) / 256, 256, 0, stream>>>(
        h3, Wd, bd, ga3, be3, mu3, va3, out, T_STEPS);
}